// Round 1
// baseline (3014.840 us; speedup 1.0000x reference)
//
#include <hip/hip_runtime.h>
#include <math.h>

#define BB 2
#define SS 2048
#define DD 512
#define HH 8
#define HDD 64
#define RANKK 128
#define DFFF 1024

__device__ __forceinline__ float wsum(float v) {
#pragma unroll
  for (int off = 32; off > 0; off >>= 1) v += __shfl_xor(v, off, 64);
  return v;
}

// ---------------- rmsnorm (wave per row, D=512) ----------------
__global__ void tsa_rmsnorm(const float* __restrict__ x, const float* __restrict__ w,
                            float* __restrict__ o, int rows) {
  int wid = blockIdx.x * 4 + (threadIdx.x >> 6);
  int lane = threadIdx.x & 63;
  if (wid >= rows) return;
  const float* xp = x + (size_t)wid * DD + lane * 8;
  float4 a = *(const float4*)xp;
  float4 b = *(const float4*)(xp + 4);
  float ss = a.x*a.x + a.y*a.y + a.z*a.z + a.w*a.w
           + b.x*b.x + b.y*b.y + b.z*b.z + b.w*b.w;
  ss = wsum(ss);
  float r = rsqrtf(ss * (1.0f / DD) + 1e-6f);
  const float* wp = w + lane * 8;
  float4 wa = *(const float4*)wp, wb = *(const float4*)(wp + 4);
  float* op = o + (size_t)wid * DD + lane * 8;
  float4 oa = {a.x*r*wa.x, a.y*r*wa.y, a.z*r*wa.z, a.w*r*wa.w};
  float4 ob = {b.x*r*wb.x, b.y*r*wb.y, b.z*r*wb.z, b.w*r*wb.w};
  *(float4*)op = oa;
  *(float4*)(op + 4) = ob;
}

// ---------------- generic fp32 GEMM 64x64 tile, BK=16 ----------------
// C[M,N] = A[M,K] @ B   (BT_: B is [N,K] row-major i.e. C=A@B^T; else B is [K,N])
// CAUSAL: A masked to k<=m (and k-tiles beyond the block skipped)
// EPI==1: C = acc + ADD (same indexing as C)
template <bool BT_, bool CAUSAL, int EPI>
__global__ void tsa_gemm(const float* __restrict__ A, const float* __restrict__ Bm,
                         const float* __restrict__ ADD, float* __restrict__ C,
                         int M, int N, int K,
                         long long sA, long long sB, long long sC) {
  A += (long long)blockIdx.z * sA;
  Bm += (long long)blockIdx.z * sB;
  C += (long long)blockIdx.z * sC;
  const int bm = blockIdx.y * 64, bn = blockIdx.x * 64;
  __shared__ float As[16][68];
  __shared__ float Bs[16][68];
  const int tid = threadIdx.x;
  const int tx = tid & 15, ty = tid >> 4;
  float acc[4][4] = {};
  const int kend = CAUSAL ? min(K, bm + 64) : K;
  for (int k0 = 0; k0 < kend; k0 += 16) {
#pragma unroll
    for (int i = 0; i < 4; i++) {
      int lin = i * 256 + tid;
      int r = lin >> 4, c = lin & 15;
      int gm = bm + r, gk = k0 + c;
      float va = 0.0f;
      if (gm < M && (!CAUSAL || gk <= gm)) va = A[(size_t)gm * K + gk];
      As[c][r] = va;
      if (BT_) {
        Bs[c][r] = Bm[(size_t)(bn + r) * K + gk];
      } else {
        int kr = lin >> 6, nc = lin & 63;
        Bs[kr][nc] = Bm[(size_t)(k0 + kr) * N + bn + nc];
      }
    }
    __syncthreads();
#pragma unroll
    for (int kk = 0; kk < 16; kk++) {
      float4 a4 = *(const float4*)&As[kk][ty * 4];
      float4 b4 = *(const float4*)&Bs[kk][tx * 4];
      float av[4] = {a4.x, a4.y, a4.z, a4.w};
      float bv[4] = {b4.x, b4.y, b4.z, b4.w};
#pragma unroll
      for (int i = 0; i < 4; i++)
#pragma unroll
        for (int j = 0; j < 4; j++)
          acc[i][j] = fmaf(av[i], bv[j], acc[i][j]);
    }
    __syncthreads();
  }
#pragma unroll
  for (int i = 0; i < 4; i++) {
    int gm = bm + ty * 4 + i;
    if (gm >= M) continue;
    size_t off = (size_t)gm * N + bn + tx * 4;
    float4 o;
    o.x = acc[i][0]; o.y = acc[i][1]; o.z = acc[i][2]; o.w = acc[i][3];
    if (EPI == 1) {
      o.x += ADD[off + 0]; o.y += ADD[off + 1];
      o.z += ADD[off + 2]; o.w += ADD[off + 3];
    }
    *(float4*)&C[off] = o;
  }
}

// ---------------- RoPE (in-place on q,k) ----------------
__global__ void tsa_rope(float* __restrict__ q, float* __restrict__ k) {
  int idx = blockIdx.x * 256 + threadIdx.x;  // B*S*H*32 threads
  int i = idx & 31;
  int h = (idx >> 5) & 7;
  int s = (idx >> 8) & (SS - 1);
  int b = idx >> 19;
  float inv = exp2f(-(float)i * (13.287712379549449f / 32.0f));  // 10000^(-i/32)
  float ang = (float)s * inv;
  float sn, cs;
  sincosf(ang, &sn, &cs);
  size_t base = ((size_t)(b * SS + s)) * DD + h * HDD + i;
  float q1 = q[base], q2 = q[base + 32];
  q[base]      = q1 * cs - q2 * sn;
  q[base + 32] = q2 * cs + q1 * sn;
  float k1 = k[base], k2 = k[base + 32];
  k[base]      = k1 * cs - k2 * sn;
  k[base + 32] = k2 * cs + k1 * sn;
}

// ---------------- causal flash attention, fp32, thread-per-row ----------------
__global__ void __launch_bounds__(64) tsa_attn(const float* __restrict__ q,
                                               const float* __restrict__ k,
                                               const float* __restrict__ v,
                                               float* __restrict__ o) {
  const int h = blockIdx.y, b = blockIdx.z;
  const int row = blockIdx.x * 64 + threadIdx.x;
  __shared__ float Ks[64][68];
  __shared__ float Vs[64][68];
  float qr[64], acc[64];
  const float* qp = q + ((size_t)(b * SS + row)) * DD + h * HDD;
#pragma unroll
  for (int i = 0; i < 16; i++) {
    float4 t = *(const float4*)(qp + i * 4);
    qr[i * 4] = t.x; qr[i * 4 + 1] = t.y; qr[i * 4 + 2] = t.z; qr[i * 4 + 3] = t.w;
  }
#pragma unroll
  for (int d = 0; d < 64; d++) acc[d] = 0.0f;
  float mx = -3.0e38f, ls = 0.0f;
  const int ntiles = blockIdx.x + 1;
  for (int kt = 0; kt < ntiles; kt++) {
    __syncthreads();
#pragma unroll
    for (int it = 0; it < 16; it++) {
      int r = it * 4 + (threadIdx.x >> 4);
      int c = (threadIdx.x & 15) * 4;
      size_t gaddr = ((size_t)(b * SS + kt * 64 + r)) * DD + h * HDD + c;
      *(float4*)&Ks[r][c] = *(const float4*)(k + gaddr);
      *(float4*)&Vs[r][c] = *(const float4*)(v + gaddr);
    }
    __syncthreads();
    const int kmax = min(64, row - kt * 64 + 1);
    for (int kk = 0; kk < kmax; kk++) {
      float s = 0.0f;
#pragma unroll
      for (int d4 = 0; d4 < 16; d4++) {
        float4 kv = *(const float4*)&Ks[kk][d4 * 4];
        s += qr[d4 * 4] * kv.x + qr[d4 * 4 + 1] * kv.y
           + qr[d4 * 4 + 2] * kv.z + qr[d4 * 4 + 3] * kv.w;
      }
      s *= 0.125f;
      float p;
      if (s > mx) {
        float corr = __expf(mx - s);
        ls *= corr;
#pragma unroll
        for (int d = 0; d < 64; d++) acc[d] *= corr;
        mx = s;
        p = 1.0f;
      } else {
        p = __expf(s - mx);
      }
      ls += p;
#pragma unroll
      for (int d4 = 0; d4 < 16; d4++) {
        float4 vv = *(const float4*)&Vs[kk][d4 * 4];
        acc[d4 * 4]     = fmaf(p, vv.x, acc[d4 * 4]);
        acc[d4 * 4 + 1] = fmaf(p, vv.y, acc[d4 * 4 + 1]);
        acc[d4 * 4 + 2] = fmaf(p, vv.z, acc[d4 * 4 + 2]);
        acc[d4 * 4 + 3] = fmaf(p, vv.w, acc[d4 * 4 + 3]);
      }
    }
  }
  float invl = 1.0f / ls;
  float* op = o + ((size_t)(b * SS + row)) * DD + h * HDD;
#pragma unroll
  for (int d4 = 0; d4 < 16; d4++) {
    float4 t = {acc[d4 * 4] * invl, acc[d4 * 4 + 1] * invl,
                acc[d4 * 4 + 2] * invl, acc[d4 * 4 + 3] * invl};
    *(float4*)(op + d4 * 4) = t;
  }
}

// ---------------- ALIF scan fused with h2 = x + mixed + spike ----------------
__global__ void tsa_alif(const float* __restrict__ mixed, const float* __restrict__ x,
                         const float* __restrict__ bt, const float* __restrict__ asw,
                         float* __restrict__ h2) {
  int idx = blockIdx.x * 256 + threadIdx.x;
  if (idx >= BB * DD) return;
  int b = idx >> 9, d = idx & 511;
  const float btd = bt[d], asd = asw[d];
  const float* mp = mixed + (size_t)b * SS * DD + d;
  const float* xp = x + (size_t)b * SS * DD + d;
  float* hp = h2 + (size_t)b * SS * DD + d;
  float vmem = 0.0f, ad = 0.0f;
  for (int t0 = 0; t0 < SS; t0 += 8) {
    float mb[8], xb[8], sp[8];
#pragma unroll
    for (int j = 0; j < 8; j++) {
      mb[j] = mp[(size_t)(t0 + j) * DD];
      xb[j] = xp[(size_t)(t0 + j) * DD];
    }
#pragma unroll
    for (int j = 0; j < 8; j++) {
      vmem = fmaf(0.99f, vmem, mb[j]);
      float th = fmaf(asd, ad, btd);
      float s = 1.0f / (1.0f + expf(-25.0f * (vmem - th)));
      vmem -= s * th;
      ad = fmaf(0.95f, ad, s);
      sp[j] = s;
    }
#pragma unroll
    for (int j = 0; j < 8; j++)
      hp[(size_t)(t0 + j) * DD] = xb[j] + mb[j] + sp[j];
  }
}

// ---------------- tree: pairwise reduce + rmsnorm(n) + res ----------------
__global__ void tsa_tree_reduce(const float* __restrict__ sin_, const float* __restrict__ tn1,
                                float* __restrict__ nout, float* __restrict__ resout,
                                int Snext) {
  int wid = blockIdx.x * 4 + (threadIdx.x >> 6);
  int lane = threadIdx.x & 63;
  int rows = BB * Snext;
  if (wid >= rows) return;
  int b = wid / Snext, j = wid - b * Snext;
  const float* r0 = sin_ + ((size_t)b * 2 * Snext + 2 * j) * DD + lane * 8;
  const float* r1 = r0 + DD;
  float4 a0 = *(const float4*)r0, a1 = *(const float4*)(r0 + 4);
  float4 b0 = *(const float4*)r1, b1 = *(const float4*)(r1 + 4);
  float ra[8] = {a0.x + b0.x, a0.y + b0.y, a0.z + b0.z, a0.w + b0.w,
                 a1.x + b1.x, a1.y + b1.y, a1.z + b1.z, a1.w + b1.w};
  float ss = 0.0f;
#pragma unroll
  for (int i = 0; i < 8; i++) ss += ra[i] * ra[i];
  ss = wsum(ss);
  float rms = rsqrtf(ss * (1.0f / DD) + 1e-6f);
  const float* wp = tn1 + lane * 8;
  float4 wa = *(const float4*)wp, wb = *(const float4*)(wp + 4);
  float wv8[8] = {wa.x, wa.y, wa.z, wa.w, wb.x, wb.y, wb.z, wb.w};
  float* np = nout + (size_t)wid * DD + lane * 8;
  float* rp = resout + (size_t)wid * DD + lane * 8;
  float4 n0 = {ra[0]*rms*wv8[0], ra[1]*rms*wv8[1], ra[2]*rms*wv8[2], ra[3]*rms*wv8[3]};
  float4 n1 = {ra[4]*rms*wv8[4], ra[5]*rms*wv8[5], ra[6]*rms*wv8[6], ra[7]*rms*wv8[7]};
  float4 r0o = {0.5f*ra[0], 0.5f*ra[1], 0.5f*ra[2], 0.5f*ra[3]};
  float4 r1o = {0.5f*ra[4], 0.5f*ra[5], 0.5f*ra[6], 0.5f*ra[7]};
  *(float4*)np = n0; *(float4*)(np + 4) = n1;
  *(float4*)rp = r0o; *(float4*)(rp + 4) = r1o;
}

// ---------------- tree: gate combine + rmsnorm ----------------
__global__ void tsa_tree_combine(const float* __restrict__ g, const float* __restrict__ n,
                                 const float* __restrict__ res, const float* __restrict__ tn2,
                                 float* __restrict__ sout, int rows) {
  int wid = blockIdx.x * 4 + (threadIdx.x >> 6);
  int lane = threadIdx.x & 63;
  if (wid >= rows) return;
  size_t base = (size_t)wid * DD + lane * 8;
  float t[8];
  float ss = 0.0f;
#pragma unroll
  for (int i = 0; i < 8; i++) {
    float gl = g[base + i];
    float gg = 1.0f / (1.0f + expf(-gl));
    float tv = gg * n[base + i] + (1.0f - gg) * res[base + i];
    t[i] = tv;
    ss += tv * tv;
  }
  ss = wsum(ss);
  float rms = rsqrtf(ss * (1.0f / DD) + 1e-6f);
#pragma unroll
  for (int i = 0; i < 8; i++) sout[base + i] = t[i] * rms * tn2[lane * 8 + i];
}

// ---------------- h3 = h2 + root; hn = rmsnorm(h3) ----------------
__global__ void tsa_h3hn(const float* __restrict__ h2, const float* __restrict__ root,
                         const float* __restrict__ fw, float* __restrict__ h3,
                         float* __restrict__ hn) {
  int wid = blockIdx.x * 4 + (threadIdx.x >> 6);
  int lane = threadIdx.x & 63;
  int b = wid >> 11;
  size_t base = (size_t)wid * DD + lane * 8;
  const float* rp = root + (size_t)b * DD + lane * 8;
  float t[8];
  float ss = 0.0f;
#pragma unroll
  for (int i = 0; i < 8; i++) {
    float tv = h2[base + i] + rp[i];
    t[i] = tv;
    ss += tv * tv;
    h3[base + i] = tv;
  }
  ss = wsum(ss);
  float rms = rsqrtf(ss * (1.0f / DD) + 1e-6f);
#pragma unroll
  for (int i = 0; i < 8; i++) hn[base + i] = t[i] * rms * fw[lane * 8 + i];
}

// ---------------- FFN up-projection fused with SwiGLU gate ----------------
// A = t1 [4096,128]; Bm = v_w [128,2048]; C = silu(A@B[:, :1024]) * (A@B[:, 1024:])
__global__ void tsa_upgate(const float* __restrict__ A, const float* __restrict__ Bm,
                           float* __restrict__ C) {
  const int bm = blockIdx.y * 64, bn = blockIdx.x * 64;
  __shared__ float As[16][68];
  __shared__ float Bs[16][68];
  __shared__ float Bs2[16][68];
  const int tid = threadIdx.x;
  const int tx = tid & 15, ty = tid >> 4;
  float acc[4][4] = {}, acc2[4][4] = {};
  for (int k0 = 0; k0 < RANKK; k0 += 16) {
#pragma unroll
    for (int i = 0; i < 4; i++) {
      int lin = i * 256 + tid;
      int r = lin >> 4, c = lin & 15;
      As[c][r] = A[(size_t)(bm + r) * RANKK + k0 + c];
      int kr = lin >> 6, nc = lin & 63;
      Bs[kr][nc]  = Bm[(size_t)(k0 + kr) * (2 * DFFF) + bn + nc];
      Bs2[kr][nc] = Bm[(size_t)(k0 + kr) * (2 * DFFF) + DFFF + bn + nc];
    }
    __syncthreads();
#pragma unroll
    for (int kk = 0; kk < 16; kk++) {
      float4 a4 = *(const float4*)&As[kk][ty * 4];
      float4 b4 = *(const float4*)&Bs[kk][tx * 4];
      float4 c4 = *(const float4*)&Bs2[kk][tx * 4];
      float av[4] = {a4.x, a4.y, a4.z, a4.w};
      float bv[4] = {b4.x, b4.y, b4.z, b4.w};
      float cv[4] = {c4.x, c4.y, c4.z, c4.w};
#pragma unroll
      for (int i = 0; i < 4; i++) {
#pragma unroll
        for (int j = 0; j < 4; j++) {
          acc[i][j] = fmaf(av[i], bv[j], acc[i][j]);
          acc2[i][j] = fmaf(av[i], cv[j], acc2[i][j]);
        }
      }
    }
    __syncthreads();
  }
#pragma unroll
  for (int i = 0; i < 4; i++) {
    int gm = bm + ty * 4 + i;
    float4 o;
    float vals[4];
#pragma unroll
    for (int j = 0; j < 4; j++) {
      float a_ = acc[i][j];
      float s = a_ / (1.0f + expf(-a_));
      vals[j] = s * acc2[i][j];
    }
    o.x = vals[0]; o.y = vals[1]; o.z = vals[2]; o.w = vals[3];
    *(float4*)&C[(size_t)gm * DFFF + bn + tx * 4] = o;
  }
}

extern "C" void kernel_launch(void* const* d_in, const int* in_sizes, int n_in,
                              void* d_out, int out_size, void* d_ws, size_t ws_size,
                              hipStream_t stream) {
  const float* x   = (const float*)d_in[0];
  const float* nw  = (const float*)d_in[1];
  const float* wq  = (const float*)d_in[2];
  const float* wk  = (const float*)d_in[3];
  const float* wv  = (const float*)d_in[4];
  const float* wo  = (const float*)d_in[5];
  const float* lat = (const float*)d_in[6];
  const float* btp = (const float*)d_in[7];
  const float* asw = (const float*)d_in[8];
  const float* gw  = (const float*)d_in[9];
  const float* tn1 = (const float*)d_in[10];
  const float* tn2 = (const float*)d_in[11];
  const float* fnw = (const float*)d_in[12];
  const float* uw  = (const float*)d_in[13];
  const float* vw  = (const float*)d_in[14];
  const float* dw  = (const float*)d_in[15];
  float* out = (float*)d_out;
  float* ws = (float*)d_ws;

  const size_t M1 = 1048576;
  float* h     = ws;            // [4096,512]
  float* q     = ws + 2 * M1;
  float* kk    = ws + 4 * M1;
  float* vv    = ws + 6 * M1;
  float* attn  = ws;            // reuse h
  float* aproj = ws + 2 * M1;   // reuse q
  float* mixed = ws + 4 * M1;   // reuse k
  float* h2    = ws + 6 * M1;   // reuse v
  float* nb    = ws;            // tree buffers (reuse attn/aproj/mixed regions)
  float* resb  = ws + 1 * M1;
  float* gb    = ws + 2 * M1;
  float* s0    = ws + 3 * M1;
  float* s1    = ws + 4 * M1;
  float* h3    = ws + 8 * M1;
  float* hn    = ws + 10 * M1;
  float* t1    = ws;            // reuse (tree dead)
  float* ffa   = ws + 1 * M1;   // [4096,1024]

  const int rows = BB * SS;  // 4096

  tsa_rmsnorm<<<rows / 4, 256, 0, stream>>>(x, nw, h, rows);

  dim3 gq(DD / 64, rows / 64, 1);
  tsa_gemm<true, false, 0><<<gq, 256, 0, stream>>>(h, wq, nullptr, q, rows, DD, DD, 0, 0, 0);
  tsa_gemm<true, false, 0><<<gq, 256, 0, stream>>>(h, wk, nullptr, kk, rows, DD, DD, 0, 0, 0);
  tsa_gemm<true, false, 0><<<gq, 256, 0, stream>>>(h, wv, nullptr, vv, rows, DD, DD, 0, 0, 0);

  tsa_rope<<<(BB * SS * HH * 32) / 256, 256, 0, stream>>>(q, kk);

  dim3 ga(SS / 64, HH, BB);
  tsa_attn<<<ga, 64, 0, stream>>>(q, kk, vv, attn);

  tsa_gemm<true, false, 0><<<gq, 256, 0, stream>>>(attn, wo, nullptr, aproj, rows, DD, DD, 0, 0, 0);

  dim3 gl(DD / 64, SS / 64, BB);
  tsa_gemm<false, true, 0><<<gl, 256, 0, stream>>>(lat, aproj, nullptr, mixed, SS, DD, SS,
                                                   0, (long long)SS * DD, (long long)SS * DD);

  tsa_alif<<<(BB * DD) / 256, 256, 0, stream>>>(mixed, x, btp, asw, h2);

  const float* sin_ = h2;
  for (int lvl = 0; lvl < 11; lvl++) {
    int Sn = 1024 >> lvl;
    int r2 = BB * Sn;
    float* sout = (lvl & 1) ? s1 : s0;
    tsa_tree_reduce<<<(r2 + 3) / 4, 256, 0, stream>>>(sin_, tn1, nb, resb, Sn);
    dim3 gt(DD / 64, (r2 + 63) / 64, 1);
    tsa_gemm<true, false, 0><<<gt, 256, 0, stream>>>(nb, gw, nullptr, gb, r2, DD, DD, 0, 0, 0);
    tsa_tree_combine<<<(r2 + 3) / 4, 256, 0, stream>>>(gb, nb, resb, tn2, sout, r2);
    sin_ = sout;
  }

  tsa_h3hn<<<rows / 4, 256, 0, stream>>>(h2, sin_, fnw, h3, hn);

  dim3 gt1(RANKK / 64, rows / 64, 1);
  tsa_gemm<false, false, 0><<<gt1, 256, 0, stream>>>(hn, uw, nullptr, t1, rows, RANKK, DD, 0, 0, 0);

  dim3 gug(DFFF / 64, rows / 64, 1);
  tsa_upgate<<<gug, 256, 0, stream>>>(t1, vw, ffa);

  dim3 gf(DD / 64, rows / 64, 1);
  tsa_gemm<false, false, 1><<<gf, 256, 0, stream>>>(ffa, dw, h3, out, rows, DD, DFFF, 0, 0, 0);
}

// Round 3
// 1080.011 us; speedup vs baseline: 2.7915x; 2.7915x over previous
//
#include <hip/hip_runtime.h>
#include <math.h>

#define BB 2
#define SS 2048
#define DD 512
#define HH 8
#define HDD 64
#define RANKK 128
#define DFFF 1024

typedef short bf16x8 __attribute__((ext_vector_type(8)));
typedef float f32x4 __attribute__((ext_vector_type(4)));

__device__ __forceinline__ short f2b(float f) {
  union { float f; unsigned u; } v; v.f = f;
  unsigned r = v.u + 0x7FFF + ((v.u >> 16) & 1);
  return (short)(r >> 16);
}
__device__ __forceinline__ float b2f(short s) {
  union { unsigned u; float f; } v; v.u = ((unsigned)(unsigned short)s) << 16;
  return v.f;
}

__device__ __forceinline__ float wsum(float v) {
#pragma unroll
  for (int off = 32; off > 0; off >>= 1) v += __shfl_xor(v, off, 64);
  return v;
}

// ---------------- rmsnorm fp32 ----------------
__global__ void tsa_rmsnorm(const float* __restrict__ x, const float* __restrict__ w,
                            float* __restrict__ o, int rows) {
  int wid = blockIdx.x * 4 + (threadIdx.x >> 6);
  int lane = threadIdx.x & 63;
  if (wid >= rows) return;
  const float* xp = x + (size_t)wid * DD + lane * 8;
  float4 a = *(const float4*)xp;
  float4 b = *(const float4*)(xp + 4);
  float ss = a.x*a.x + a.y*a.y + a.z*a.z + a.w*a.w
           + b.x*b.x + b.y*b.y + b.z*b.z + b.w*b.w;
  ss = wsum(ss);
  float r = rsqrtf(ss * (1.0f / DD) + 1e-6f);
  const float* wp = w + lane * 8;
  float4 wa = *(const float4*)wp, wb = *(const float4*)(wp + 4);
  float* op = o + (size_t)wid * DD + lane * 8;
  float4 oa = {a.x*r*wa.x, a.y*r*wa.y, a.z*r*wa.z, a.w*r*wa.w};
  float4 ob = {b.x*r*wb.x, b.y*r*wb.y, b.z*r*wb.z, b.w*r*wb.w};
  *(float4*)op = oa;
  *(float4*)(op + 4) = ob;
}

// ---------------- RoPE fp32 in-place ----------------
__global__ void tsa_rope(float* __restrict__ q, float* __restrict__ k) {
  int idx = blockIdx.x * 256 + threadIdx.x;
  int i = idx & 31;
  int h = (idx >> 5) & 7;
  int s = (idx >> 8) & (SS - 1);
  int b = idx >> 19;
  float inv = exp2f(-(float)i * (13.287712379549449f / 32.0f));
  float ang = (float)s * inv;
  float sn, cs;
  sincosf(ang, &sn, &cs);
  size_t base = ((size_t)(b * SS + s)) * DD + h * HDD + i;
  float q1 = q[base], q2 = q[base + 32];
  q[base]      = q1 * cs - q2 * sn;
  q[base + 32] = q2 * cs + q1 * sn;
  float k1 = k[base], k2 = k[base + 32];
  k[base]      = k1 * cs - k2 * sn;
  k[base + 32] = k2 * cs + k1 * sn;
}

// ======================= split-precision GEMM =======================
// A fp32 [M][K]; B fp32 [N][K] (BL=0) or [K][N] (BL=1). C = A@B(^T).
// SPLIT: hi/lo bf16 decomposition, 3-term MFMA (~fp32 operand precision).
// TRILA: mask A to k<=m (lat); OM: 0 f32 [M][N]; 1 vT scatter; 2 aprojT; 3 +=ADD.
template <int BL, bool SPLIT, bool TRILA, int OM>
__global__ __launch_bounds__(256) void sgemm(const float* __restrict__ A,
                                             const float* __restrict__ Bm,
                                             const float* __restrict__ ADD,
                                             float* __restrict__ C,
                                             int M, int N, int K,
                                             long long sA, long long sB, long long sC) {
  A += (long long)blockIdx.z * sA;
  Bm += (long long)blockIdx.z * sB;
  C += (long long)blockIdx.z * sC;
  __shared__ short Ah[128 * 32];
  __shared__ short Al[SPLIT ? 128 * 32 : 64];
  __shared__ short Bh[128 * 32];
  __shared__ short Bl[SPLIT ? 128 * 32 : 64];
  const int tid = threadIdx.x, l = tid & 63, w = tid >> 6;
  const int wr = (w >> 1) * 64, wc = (w & 1) * 64;
  const int bm = blockIdx.y * 128, bn = blockIdx.x * 128;
  f32x4 acc[4][4] = {};
  const int kend = TRILA ? min(K, bm + 128) : K;
  for (int k0 = 0; k0 < kend; k0 += 32) {
    // stage A
#pragma unroll
    for (int i = 0; i < 4; i++) {
      int lin = i * 256 + tid;
      int row = lin >> 3, f4 = lin & 7;
      int gr = min(bm + row, M - 1);
      float4 v = *(const float4*)(A + (size_t)gr * K + k0 + f4 * 4);
      if (TRILA) {
        int kc = k0 + f4 * 4;
        if (kc + 0 > gr) v.x = 0.0f;
        if (kc + 1 > gr) v.y = 0.0f;
        if (kc + 2 > gr) v.z = 0.0f;
        if (kc + 3 > gr) v.w = 0.0f;
      }
      int off = row * 32 + (((f4 >> 1) ^ ((row >> 1) & 3)) << 3) + (f4 & 1) * 4;
      short4 hh;
      hh.x = f2b(v.x); hh.y = f2b(v.y); hh.z = f2b(v.z); hh.w = f2b(v.w);
      *(short4*)(Ah + off) = hh;
      if (SPLIT) {
        short4 lo;
        lo.x = f2b(v.x - b2f(hh.x)); lo.y = f2b(v.y - b2f(hh.y));
        lo.z = f2b(v.z - b2f(hh.z)); lo.w = f2b(v.w - b2f(hh.w));
        *(short4*)(Al + off) = lo;
      }
    }
    // stage B
    if (BL == 0) {
#pragma unroll
      for (int i = 0; i < 4; i++) {
        int lin = i * 256 + tid;
        int row = lin >> 3, f4 = lin & 7;
        int gr = min(bn + row, N - 1);
        float4 v = *(const float4*)(Bm + (size_t)gr * K + k0 + f4 * 4);
        int off = row * 32 + (((f4 >> 1) ^ ((row >> 1) & 3)) << 3) + (f4 & 1) * 4;
        short4 hh;
        hh.x = f2b(v.x); hh.y = f2b(v.y); hh.z = f2b(v.z); hh.w = f2b(v.w);
        *(short4*)(Bh + off) = hh;
        if (SPLIT) {
          short4 lo;
          lo.x = f2b(v.x - b2f(hh.x)); lo.y = f2b(v.y - b2f(hh.y));
          lo.z = f2b(v.z - b2f(hh.z)); lo.w = f2b(v.w - b2f(hh.w));
          *(short4*)(Bl + off) = lo;
        }
      }
    } else {
#pragma unroll
      for (int i = 0; i < 4; i++) {
        int lin = i * 256 + tid;
        int kk = lin >> 5, f4n = lin & 31;
        float4 v = *(const float4*)(Bm + (size_t)(k0 + kk) * N + bn + f4n * 4);
        float vv[4] = {v.x, v.y, v.z, v.w};
#pragma unroll
        for (int e = 0; e < 4; e++) {
          int row = f4n * 4 + e;
          int off = row * 32 + (((kk >> 3) ^ ((row >> 1) & 3)) << 3) + (kk & 7);
          short hi = f2b(vv[e]);
          Bh[off] = hi;
          if (SPLIT) Bl[off] = f2b(vv[e] - b2f(hi));
        }
      }
    }
    __syncthreads();
    bf16x8 ah[4], bh[4], al_[4], bl_[4];
#pragma unroll
    for (int m = 0; m < 4; m++) {
      int r = wr + m * 16 + (l & 15);
      int go = (((l >> 4) ^ ((r >> 1) & 3)) << 3);
      ah[m] = *(const bf16x8*)(Ah + r * 32 + go);
      if (SPLIT) al_[m] = *(const bf16x8*)(Al + r * 32 + go);
    }
#pragma unroll
    for (int n = 0; n < 4; n++) {
      int r = wc + n * 16 + (l & 15);
      int go = (((l >> 4) ^ ((r >> 1) & 3)) << 3);
      bh[n] = *(const bf16x8*)(Bh + r * 32 + go);
      if (SPLIT) bl_[n] = *(const bf16x8*)(Bl + r * 32 + go);
    }
#pragma unroll
    for (int m = 0; m < 4; m++)
#pragma unroll
      for (int n = 0; n < 4; n++) {
        acc[m][n] = __builtin_amdgcn_mfma_f32_16x16x32_bf16(ah[m], bh[n], acc[m][n], 0, 0, 0);
        if (SPLIT) {
          acc[m][n] = __builtin_amdgcn_mfma_f32_16x16x32_bf16(ah[m], bl_[n], acc[m][n], 0, 0, 0);
          acc[m][n] = __builtin_amdgcn_mfma_f32_16x16x32_bf16(al_[m], bh[n], acc[m][n], 0, 0, 0);
        }
      }
    __syncthreads();
  }
#pragma unroll
  for (int m = 0; m < 4; m++)
#pragma unroll
    for (int n = 0; n < 4; n++) {
      int gn = bn + wc + n * 16 + (l & 15);
#pragma unroll
      for (int j = 0; j < 4; j++) {
        int gm = bm + wr + m * 16 + (l >> 4) * 4 + j;
        if (gm >= M || gn >= N) continue;
        float v = acc[m][n][j];
        if (OM == 0) {
          C[(size_t)gm * N + gn] = v;
        } else if (OM == 1) {  // vT: [b][h][64][S]
          int b = gm >> 11, s2 = gm & (SS - 1);
          int hh2 = gn >> 6, d = gn & 63;
          C[(((size_t)(b * HH + hh2)) * HDD + d) * SS + s2] = v;
        } else if (OM == 2) {  // aprojT: [b][512][S]
          int b = gm >> 11, s2 = gm & (SS - 1);
          C[((size_t)b * DD + gn) * SS + s2] = v;
        } else {
          size_t off = (size_t)gm * N + gn;
          C[off] = v + ADD[off];
        }
      }
    }
}

// ======================= split-precision flash attention =======================
__global__ __launch_bounds__(256) void attn_f(const float* __restrict__ q,
                                              const float* __restrict__ k,
                                              const float* __restrict__ vT,
                                              float* __restrict__ attn) {
  const int h = blockIdx.y, b = blockIdx.z;
  const int q0 = blockIdx.x * 64;
  const int tid = threadIdx.x, w = tid >> 6, l = tid & 63;
  const int lg = l >> 4, ll = l & 15;
  __shared__ short Kh[64 * 64], Kl[64 * 64];
  __shared__ short Vh[64 * 64], Vl[64 * 64];
  __shared__ short Ph[64 * 64], Pl[64 * 64];

  // stage Q (split) into Ph/Pl
#pragma unroll
  for (int i = 0; i < 4; i++) {
    int lin = i * 256 + tid;
    int row = lin >> 4, f4 = lin & 15;
    float4 v = *(const float4*)(q + ((size_t)(b * SS + q0 + row)) * DD + h * HDD + f4 * 4);
    int off = row * 64 + (((f4 >> 1) ^ (row & 7)) << 3) + (f4 & 1) * 4;
    short4 hh, lo;
    hh.x = f2b(v.x); hh.y = f2b(v.y); hh.z = f2b(v.z); hh.w = f2b(v.w);
    lo.x = f2b(v.x - b2f(hh.x)); lo.y = f2b(v.y - b2f(hh.y));
    lo.z = f2b(v.z - b2f(hh.z)); lo.w = f2b(v.w - b2f(hh.w));
    *(short4*)(Ph + off) = hh;
    *(short4*)(Pl + off) = lo;
  }
  __syncthreads();
  bf16x8 qfh[2], qfl[2];
  {
    int qr = w * 16 + ll;
#pragma unroll
    for (int ks = 0; ks < 2; ks++) {
      int g = (ks * 4 + lg) ^ (qr & 7);
      qfh[ks] = *(const bf16x8*)(Ph + qr * 64 + g * 8);
      qfl[ks] = *(const bf16x8*)(Pl + qr * 64 + g * 8);
    }
  }
  __syncthreads();

  f32x4 o[4] = {};
  float mrow[4] = {-1e30f, -1e30f, -1e30f, -1e30f};
  float lsum[4] = {};
  const int qrow0 = q0 + w * 16 + lg * 4;
  const int ntiles = blockIdx.x + 1;

  for (int kt = 0; kt < ntiles; kt++) {
#pragma unroll
    for (int i = 0; i < 4; i++) {
      int lin = i * 256 + tid;
      int row = lin >> 4, f4 = lin & 15;
      int off = row * 64 + (((f4 >> 1) ^ (row & 7)) << 3) + (f4 & 1) * 4;
      float4 kv = *(const float4*)(k + ((size_t)(b * SS + kt * 64 + row)) * DD + h * HDD + f4 * 4);
      short4 hh, lo;
      hh.x = f2b(kv.x); hh.y = f2b(kv.y); hh.z = f2b(kv.z); hh.w = f2b(kv.w);
      lo.x = f2b(kv.x - b2f(hh.x)); lo.y = f2b(kv.y - b2f(hh.y));
      lo.z = f2b(kv.z - b2f(hh.z)); lo.w = f2b(kv.w - b2f(hh.w));
      *(short4*)(Kh + off) = hh;
      *(short4*)(Kl + off) = lo;
      float4 vv = *(const float4*)(vT + (((size_t)(b * HH + h)) * HDD + row) * SS + kt * 64 + f4 * 4);
      hh.x = f2b(vv.x); hh.y = f2b(vv.y); hh.z = f2b(vv.z); hh.w = f2b(vv.w);
      lo.x = f2b(vv.x - b2f(hh.x)); lo.y = f2b(vv.y - b2f(hh.y));
      lo.z = f2b(vv.z - b2f(hh.z)); lo.w = f2b(vv.w - b2f(hh.w));
      *(short4*)(Vh + off) = hh;
      *(short4*)(Vl + off) = lo;
    }
    __syncthreads();

    f32x4 sv[4] = {};
#pragma unroll
    for (int nf = 0; nf < 4; nf++) {
      int r = nf * 16 + ll;
#pragma unroll
      for (int ks = 0; ks < 2; ks++) {
        int g = (ks * 4 + lg) ^ (r & 7);
        bf16x8 kh = *(const bf16x8*)(Kh + r * 64 + g * 8);
        bf16x8 kl = *(const bf16x8*)(Kl + r * 64 + g * 8);
        sv[nf] = __builtin_amdgcn_mfma_f32_16x16x32_bf16(qfh[ks], kh, sv[nf], 0, 0, 0);
        sv[nf] = __builtin_amdgcn_mfma_f32_16x16x32_bf16(qfh[ks], kl, sv[nf], 0, 0, 0);
        sv[nf] = __builtin_amdgcn_mfma_f32_16x16x32_bf16(qfl[ks], kh, sv[nf], 0, 0, 0);
      }
    }
#pragma unroll
    for (int nf = 0; nf < 4; nf++) {
      int kpos = kt * 64 + nf * 16 + ll;
#pragma unroll
      for (int j = 0; j < 4; j++) {
        float v = sv[nf][j] * 0.125f;
        sv[nf][j] = (kpos > qrow0 + j) ? -1e30f : v;
      }
    }
    float cf[4];
#pragma unroll
    for (int j = 0; j < 4; j++) {
      float r = fmaxf(fmaxf(sv[0][j], sv[1][j]), fmaxf(sv[2][j], sv[3][j]));
      r = fmaxf(r, __shfl_xor(r, 1)); r = fmaxf(r, __shfl_xor(r, 2));
      r = fmaxf(r, __shfl_xor(r, 4)); r = fmaxf(r, __shfl_xor(r, 8));
      float mn = fmaxf(mrow[j], r);
      cf[j] = __expf(mrow[j] - mn);
      mrow[j] = mn;
    }
    float ps[4] = {};
#pragma unroll
    for (int nf = 0; nf < 4; nf++)
#pragma unroll
      for (int j = 0; j < 4; j++) {
        float p = __expf(sv[nf][j] - mrow[j]);
        sv[nf][j] = p;
        ps[j] += p;
      }
#pragma unroll
    for (int j = 0; j < 4; j++) {
      float r = ps[j];
      r += __shfl_xor(r, 1); r += __shfl_xor(r, 2);
      r += __shfl_xor(r, 4); r += __shfl_xor(r, 8);
      lsum[j] = lsum[j] * cf[j] + r;
    }
#pragma unroll
    for (int nf = 0; nf < 4; nf++)
#pragma unroll
      for (int j = 0; j < 4; j++) o[nf][j] *= cf[j];
    // write P split into Ph/Pl
#pragma unroll
    for (int nf = 0; nf < 4; nf++)
#pragma unroll
      for (int j = 0; j < 4; j++) {
        int rowP = w * 16 + lg * 4 + j;
        int col = nf * 16 + ll;
        int off = rowP * 64 + (((col >> 3) ^ (rowP & 7)) << 3) + (col & 7);
        float p = sv[nf][j];
        short hi = f2b(p);
        Ph[off] = hi;
        Pl[off] = f2b(p - b2f(hi));
      }
    __syncthreads();
    bf16x8 pfh[2], pfl[2];
    {
      int rowA = w * 16 + ll;
#pragma unroll
      for (int ks = 0; ks < 2; ks++) {
        int g = (ks * 4 + lg) ^ (rowA & 7);
        pfh[ks] = *(const bf16x8*)(Ph + rowA * 64 + g * 8);
        pfl[ks] = *(const bf16x8*)(Pl + rowA * 64 + g * 8);
      }
    }
#pragma unroll
    for (int nf = 0; nf < 4; nf++) {
      int r = nf * 16 + ll;
#pragma unroll
      for (int ks = 0; ks < 2; ks++) {
        int g = (ks * 4 + lg) ^ (r & 7);
        bf16x8 vh = *(const bf16x8*)(Vh + r * 64 + g * 8);
        bf16x8 vl = *(const bf16x8*)(Vl + r * 64 + g * 8);
        o[nf] = __builtin_amdgcn_mfma_f32_16x16x32_bf16(pfh[ks], vh, o[nf], 0, 0, 0);
        o[nf] = __builtin_amdgcn_mfma_f32_16x16x32_bf16(pfh[ks], vl, o[nf], 0, 0, 0);
        o[nf] = __builtin_amdgcn_mfma_f32_16x16x32_bf16(pfl[ks], vh, o[nf], 0, 0, 0);
      }
    }
    __syncthreads();
  }
  float inv[4];
#pragma unroll
  for (int j = 0; j < 4; j++) inv[j] = 1.0f / lsum[j];
#pragma unroll
  for (int nf = 0; nf < 4; nf++)
#pragma unroll
    for (int j = 0; j < 4; j++)
      attn[((size_t)(b * SS + qrow0 + j)) * DD + h * HDD + nf * 16 + ll] = o[nf][j] * inv[j];
}

// ======================= ALIF scan (fp32) =======================
__global__ void tsa_alif(const float* __restrict__ mixed, const float* __restrict__ x,
                         const float* __restrict__ bt, const float* __restrict__ asw,
                         float* __restrict__ h2) {
  int idx = blockIdx.x * 256 + threadIdx.x;
  if (idx >= BB * DD) return;
  int b = idx >> 9, d = idx & 511;
  const float btd = bt[d], asd = asw[d];
  const float* mp = mixed + (size_t)b * SS * DD + d;
  const float* xp = x + (size_t)b * SS * DD + d;
  float* hp = h2 + (size_t)b * SS * DD + d;
  float vmem = 0.0f, ad = 0.0f;
  for (int t0 = 0; t0 < SS; t0 += 8) {
    float mb[8], xb[8], sp[8];
#pragma unroll
    for (int j = 0; j < 8; j++) {
      mb[j] = mp[(size_t)(t0 + j) * DD];
      xb[j] = xp[(size_t)(t0 + j) * DD];
    }
#pragma unroll
    for (int j = 0; j < 8; j++) {
      vmem = fmaf(0.99f, vmem, mb[j]);
      float th = fmaf(asd, ad, btd);
      float s = 1.0f / (1.0f + expf(-25.0f * (vmem - th)));
      vmem -= s * th;
      ad = fmaf(0.95f, ad, s);
      sp[j] = s;
    }
#pragma unroll
    for (int j = 0; j < 8; j++)
      hp[(size_t)(t0 + j) * DD] = xb[j] + mb[j] + sp[j];
  }
}

// ======================= tree kernels (fp32) =======================
__global__ void tree_reduce_f(const float* __restrict__ sin_, const float* __restrict__ tn1,
                              float* __restrict__ nb, int Sn) {
  int wid = blockIdx.x * 4 + (threadIdx.x >> 6);
  int lane = threadIdx.x & 63;
  int rows = BB * Sn;
  if (wid >= rows) return;
  int b = wid / Sn, j = wid - b * Sn;
  const float* r0 = sin_ + ((size_t)(b * 2 * Sn + 2 * j)) * DD + lane * 8;
  const float* r1 = r0 + DD;
  float4 a0 = *(const float4*)r0, a1 = *(const float4*)(r0 + 4);
  float4 b0 = *(const float4*)r1, b1 = *(const float4*)(r1 + 4);
  float ra[8] = {a0.x + b0.x, a0.y + b0.y, a0.z + b0.z, a0.w + b0.w,
                 a1.x + b1.x, a1.y + b1.y, a1.z + b1.z, a1.w + b1.w};
  float ss = 0.0f;
#pragma unroll
  for (int i = 0; i < 8; i++) ss += ra[i] * ra[i];
  ss = wsum(ss);
  float rms = rsqrtf(ss * (1.0f / DD) + 1e-6f);
  const float* wp = tn1 + lane * 8;
  float4 wa = *(const float4*)wp, wb = *(const float4*)(wp + 4);
  float wv8[8] = {wa.x, wa.y, wa.z, wa.w, wb.x, wb.y, wb.z, wb.w};
  float* np = nb + (size_t)wid * DD + lane * 8;
  float4 n0 = {ra[0]*rms*wv8[0], ra[1]*rms*wv8[1], ra[2]*rms*wv8[2], ra[3]*rms*wv8[3]};
  float4 n1 = {ra[4]*rms*wv8[4], ra[5]*rms*wv8[5], ra[6]*rms*wv8[6], ra[7]*rms*wv8[7]};
  *(float4*)np = n0;
  *(float4*)(np + 4) = n1;
}

__global__ void tree_combine_f(const float* __restrict__ g, const float* __restrict__ nb,
                               const float* __restrict__ sin_, const float* __restrict__ tn2,
                               float* __restrict__ sout, int Sn) {
  int wid = blockIdx.x * 4 + (threadIdx.x >> 6);
  int lane = threadIdx.x & 63;
  int rows = BB * Sn;
  if (wid >= rows) return;
  int b = wid / Sn, j = wid - b * Sn;
  const float* r0 = sin_ + ((size_t)(b * 2 * Sn + 2 * j)) * DD + lane * 8;
  const float* r1 = r0 + DD;
  float4 a0 = *(const float4*)r0, a1 = *(const float4*)(r0 + 4);
  float4 b0 = *(const float4*)r1, b1 = *(const float4*)(r1 + 4);
  float res[8] = {0.5f*(a0.x + b0.x), 0.5f*(a0.y + b0.y), 0.5f*(a0.z + b0.z), 0.5f*(a0.w + b0.w),
                  0.5f*(a1.x + b1.x), 0.5f*(a1.y + b1.y), 0.5f*(a1.z + b1.z), 0.5f*(a1.w + b1.w)};
  size_t base = (size_t)wid * DD + lane * 8;
  float t[8];
  float ss = 0.0f;
#pragma unroll
  for (int i = 0; i < 8; i++) {
    float gg = 1.0f / (1.0f + expf(-g[base + i]));
    float tv = gg * nb[base + i] + (1.0f - gg) * res[i];
    t[i] = tv;
    ss += tv * tv;
  }
  ss = wsum(ss);
  float rms = rsqrtf(ss * (1.0f / DD) + 1e-6f);
#pragma unroll
  for (int i = 0; i < 8; i++) sout[base + i] = t[i] * rms * tn2[lane * 8 + i];
}

__global__ void h3hn_f(const float* __restrict__ h2, const float* __restrict__ root,
                       const float* __restrict__ fw, float* __restrict__ h3,
                       float* __restrict__ hn) {
  int wid = blockIdx.x * 4 + (threadIdx.x >> 6);
  int lane = threadIdx.x & 63;
  int b = wid >> 11;
  size_t base = (size_t)wid * DD + lane * 8;
  const float* rp = root + (size_t)b * DD + lane * 8;
  float t[8];
  float ss = 0.0f;
#pragma unroll
  for (int i = 0; i < 8; i++) {
    float tv = h2[base + i] + rp[i];
    t[i] = tv;
    ss += tv * tv;
    h3[base + i] = tv;
  }
  ss = wsum(ss);
  float rms = rsqrtf(ss * (1.0f / DD) + 1e-6f);
#pragma unroll
  for (int i = 0; i < 8; i++) hn[base + i] = t[i] * rms * fw[lane * 8 + i];
}

// ======================= upgate (single bf16) =======================
__global__ __launch_bounds__(256) void upgate_f(const float* __restrict__ A,
                                                const float* __restrict__ Bv,
                                                float* __restrict__ ffa) {
  __shared__ short Ah[128 * 32];
  __shared__ short B1h[128 * 32];
  __shared__ short B2h[128 * 32];
  const int tid = threadIdx.x, l = tid & 63, w = tid >> 6;
  const int wr = (w >> 1) * 64, wc = (w & 1) * 64;
  const int bm = blockIdx.y * 128, bn = blockIdx.x * 128;
  f32x4 acc1[4][4] = {}, acc2[4][4] = {};
  for (int k0 = 0; k0 < RANKK; k0 += 32) {
#pragma unroll
    for (int i = 0; i < 4; i++) {
      int lin = i * 256 + tid;
      int row = lin >> 3, f4 = lin & 7;
      float4 v = *(const float4*)(A + (size_t)(bm + row) * RANKK + k0 + f4 * 4);
      int off = row * 32 + (((f4 >> 1) ^ ((row >> 1) & 3)) << 3) + (f4 & 1) * 4;
      short4 hh;
      hh.x = f2b(v.x); hh.y = f2b(v.y); hh.z = f2b(v.z); hh.w = f2b(v.w);
      *(short4*)(Ah + off) = hh;
    }
#pragma unroll
    for (int i = 0; i < 4; i++) {
      int lin = i * 256 + tid;
      int kk = lin >> 5, f4n = lin & 31;
      float4 v1 = *(const float4*)(Bv + (size_t)(k0 + kk) * (2 * DFFF) + bn + f4n * 4);
      float4 v2 = *(const float4*)(Bv + (size_t)(k0 + kk) * (2 * DFFF) + DFFF + bn + f4n * 4);
      float a1[4] = {v1.x, v1.y, v1.z, v1.w};
      float a2[4] = {v2.x, v2.y, v2.z, v2.w};
#pragma unroll
      for (int e = 0; e < 4; e++) {
        int row = f4n * 4 + e;
        int off = row * 32 + (((kk >> 3) ^ ((row >> 1) & 3)) << 3) + (kk & 7);
        B1h[off] = f2b(a1[e]);
        B2h[off] = f2b(a2[e]);
      }
    }
    __syncthreads();
    bf16x8 ah[4], b1[4], b2[4];
#pragma unroll
    for (int m = 0; m < 4; m++) {
      int r = wr + m * 16 + (l & 15);
      int go = (((l >> 4) ^ ((r >> 1) & 3)) << 3);
      ah[m] = *(const bf16x8*)(Ah + r * 32 + go);
    }
#pragma unroll
    for (int n = 0; n < 4; n++) {
      int r = wc + n * 16 + (l & 15);
      int go = (((l >> 4) ^ ((r >> 1) & 3)) << 3);
      b1[n] = *(const bf16x8*)(B1h + r * 32 + go);
      b2[n] = *(const bf16x8*)(B2h + r * 32 + go);
    }
#pragma unroll
    for (int m = 0; m < 4; m++)
#pragma unroll
      for (int n = 0; n < 4; n++) {
        acc1[m][n] = __builtin_amdgcn_mfma_f32_16x16x32_bf16(ah[m], b1[n], acc1[m][n], 0, 0, 0);
        acc2[m][n] = __builtin_amdgcn_mfma_f32_16x16x32_bf16(ah[m], b2[n], acc2[m][n], 0, 0, 0);
      }
    __syncthreads();
  }
#pragma unroll
  for (int m = 0; m < 4; m++)
#pragma unroll
    for (int n = 0; n < 4; n++) {
      int gn = bn + wc + n * 16 + (l & 15);
#pragma unroll
      for (int j = 0; j < 4; j++) {
        int gm = bm + wr + m * 16 + (l >> 4) * 4 + j;
        float a = acc1[m][n][j];
        float s = a / (1.0f + __expf(-a));
        ffa[(size_t)gm * DFFF + gn] = s * acc2[m][n][j];
      }
    }
}

// ======================= launch =======================
extern "C" void kernel_launch(void* const* d_in, const int* in_sizes, int n_in,
                              void* d_out, int out_size, void* d_ws, size_t ws_size,
                              hipStream_t stream) {
  const float* x   = (const float*)d_in[0];
  const float* nw  = (const float*)d_in[1];
  const float* wq  = (const float*)d_in[2];
  const float* wk  = (const float*)d_in[3];
  const float* wv  = (const float*)d_in[4];
  const float* wo  = (const float*)d_in[5];
  const float* lat = (const float*)d_in[6];
  const float* btp = (const float*)d_in[7];
  const float* asw = (const float*)d_in[8];
  const float* gw  = (const float*)d_in[9];
  const float* tn1 = (const float*)d_in[10];
  const float* tn2 = (const float*)d_in[11];
  const float* fnw = (const float*)d_in[12];
  const float* uw  = (const float*)d_in[13];
  const float* vw  = (const float*)d_in[14];
  const float* dw  = (const float*)d_in[15];
  float* out = (float*)d_out;
  char* W = (char*)d_ws;

  float* fA = (float*)(W);                       // 8MB: h / attn / nb+gb / hn
  float* fB = (float*)(W + (size_t)(8u << 20));  // q / aprojT / ffa
  float* fC = (float*)(W + (size_t)(16u << 20)); // k / mixed / ffa-hi
  float* fD = (float*)(W + (size_t)(24u << 20)); // vT / s0+s1+t1
  float* fE = (float*)(W + (size_t)(32u << 20)); // h2

  float* h = fA;
  float* q = fB;
  float* kbuf = fC;
  float* vT = fD;
  float* attn = fA;
  float* aprojT = fB;
  float* mixed = fC;
  float* h2 = fE;
  float* nb = fA;
  float* gb = fA + 1048576;
  float* s0 = fD;
  float* s1 = fD + 1048576;
  float* t1 = fD + 1572864;
  float* hn = fA;
  float* ffa = fB;  // 16MB spanning fB..fC

  const int rows = BB * SS;  // 4096

  tsa_rmsnorm<<<rows / 4, 256, 0, stream>>>(x, nw, h, rows);

  sgemm<0, true, false, 0><<<dim3(4, 32), 256, 0, stream>>>(h, wq, nullptr, q,
                                                            rows, DD, DD, 0, 0, 0);
  sgemm<0, true, false, 0><<<dim3(4, 32), 256, 0, stream>>>(h, wk, nullptr, kbuf,
                                                            rows, DD, DD, 0, 0, 0);
  sgemm<0, true, false, 1><<<dim3(4, 32), 256, 0, stream>>>(h, wv, nullptr, vT,
                                                            rows, DD, DD, 0, 0, 0);

  tsa_rope<<<(BB * SS * HH * 32) / 256, 256, 0, stream>>>(q, kbuf);

  attn_f<<<dim3(32, HH, BB), 256, 0, stream>>>(q, kbuf, vT, attn);

  sgemm<0, true, false, 2><<<dim3(4, 32), 256, 0, stream>>>(attn, wo, nullptr, aprojT,
                                                            rows, DD, DD, 0, 0, 0);

  sgemm<0, true, true, 0><<<dim3(4, 16, 2), 256, 0, stream>>>(
      lat, aprojT, nullptr, mixed, SS, DD, SS, 0, (long long)DD * SS, (long long)SS * DD);

  tsa_alif<<<4, 256, 0, stream>>>(mixed, x, btp, asw, h2);

  const float* sin_ = h2;
  for (int lvl = 0; lvl < 11; lvl++) {
    int Sn = 1024 >> lvl;
    int r2 = BB * Sn;
    float* sout = (lvl & 1) ? s1 : s0;
    tree_reduce_f<<<(r2 + 3) / 4, 256, 0, stream>>>(sin_, tn1, nb, Sn);
    sgemm<0, false, false, 0><<<dim3(4, (r2 + 127) / 128), 256, 0, stream>>>(
        nb, gw, nullptr, gb, r2, DD, DD, 0, 0, 0);
    tree_combine_f<<<(r2 + 3) / 4, 256, 0, stream>>>(gb, nb, sin_, tn2, sout, Sn);
    sin_ = sout;
  }

  h3hn_f<<<rows / 4, 256, 0, stream>>>(h2, sin_, fnw, out, hn);

  sgemm<1, false, false, 0><<<dim3(1, 32), 256, 0, stream>>>(hn, uw, nullptr, t1,
                                                             rows, RANKK, DD, 0, 0, 0);
  upgate_f<<<dim3(8, 32), 256, 0, stream>>>(t1, vw, ffa);
  sgemm<1, false, false, 3><<<dim3(4, 32), 256, 0, stream>>>(ffa, dw, out, out,
                                                             rows, DD, DFFF, 0, 0, 0);
}